// Round 6
// baseline (294.074 us; speedup 1.0000x reference)
//
#include <hip/hip_runtime.h>
#include <hip/hip_bf16.h>

#define N_TOK  1728     // 12*12*12
#define CDIM   64
#define NHEADS 32       // head_dim = 2
#define QTILES 27       // 1728 / 64
#define NBLK   432      // persistent blocks; 8 waves each -> 3456 waves
#define NWAVE  (NBLK * 8)
#define SCALE  0.70710678118654752f    // 1/sqrt(2)
#define LOG2E  1.44269504088896340736f
#define JW     8                       // waves per block (j-split factor)
#define JCHUNK (N_TOK / JW)            // 216 keys per wave

// ---- dtype-adaptive load: f32=1 -> fp32 buffer, 0 -> bf16 buffer ----
__device__ __forceinline__ float ldin(const void* p, int i, int f32) {
    if (f32) return ((const float*)p)[i];
    union { unsigned int b; float f; } c;
    c.b = ((unsigned int)((const unsigned short*)p)[i]) << 16;
    return c.f;
}

// ---- wave-local dtype sniff: fp32 bits read as bf16 show exp=0xFF / huge ----
__device__ __forceinline__ int sniff_f32(const void* x) {
    union { unsigned int b; float f; } c;
    c.b = ((unsigned int)((const unsigned short*)x)[threadIdx.x & 63]) << 16;
    int bad = (((c.b >> 23) & 0xFF) == 0xFF) || (fabsf(c.f) > 1e10f);
    return (__ballot(bad) != 0ULL) ? 1 : 0;
}

// ---- software grid barrier (all NBLK blocks provably co-resident) ----
// release: threadfence + device-scope atomicAdd; acquire: agent-scope load.
__device__ __forceinline__ void grid_barrier(unsigned int* cnt) {
    __syncthreads();
    if (threadIdx.x == 0) {
        __threadfence();                     // device-scope release
        atomicAdd(cnt, 1u);                  // device-scope by default (m20)
        while (__hip_atomic_load(cnt, __ATOMIC_ACQUIRE,
                                 __HIP_MEMORY_SCOPE_AGENT) < (unsigned)NBLK)
            __builtin_amdgcn_s_sleep(2);
    }
    __syncthreads();
}

// ================= single fused persistent kernel =================
// 432 blocks x 512 threads. __launch_bounds__(512,4) -> VGPR<=128 ->
// >=2 blocks/CU -> capacity >=512 > 432: co-residency guaranteed (no deadlock).
__global__ void __launch_bounds__(512, 4)
fused_kernel(const void* __restrict__ x, const void* __restrict__ w_qkv,
             const void* __restrict__ w_proj, const void* __restrict__ b_proj,
             unsigned int* __restrict__ bar,
             float* __restrict__ Q, float* __restrict__ KV,
             float* __restrict__ wT, __hip_bfloat16* __restrict__ Ob,
             void* __restrict__ out) {
    __shared__ float redbuf[JW * 64 * 3];   // 6 KB, reused across phases
    const int f    = sniff_f32(x);
    const int tid  = threadIdx.x;
    const int lane = tid & 63;
    const int wav  = tid >> 6;
    const int b    = blockIdx.x;
    const int W0   = b * JW + wav;          // global wave id, [0, 3456)

    // ---------------- Phase 1: QKV projection + w_proj transpose ----------------
    for (int W = W0; W < 192 * QTILES + 64; W += NWAVE) {   // 5248 wave-tasks
        if (W < 192 * QTILES) {
            int jj   = W / QTILES;            // uniform weight row -> s_loads
            int n    = (W % QTILES) * 64 + lane;   // coalesced over x
            float acc = 0.0f;
#pragma unroll 8
            for (int c = 0; c < CDIM; ++c)
                acc = fmaf(ldin(x, c * N_TOK + n, f),
                           ldin(w_qkv, jj * CDIM + c, f), acc);
            int which = jj >> 6;
            int hd    = jj & 63;
            int h = hd >> 1, d = hd & 1;
            if (which == 0)
                Q[h * N_TOK * 2 + n * 2 + d] = acc * (SCALE * LOG2E);
            else
                KV[h * N_TOK * 4 + n * 4 + ((which == 1) ? d : 2 + d)] = acc;
        } else {                              // 64 waves transpose w_proj -> fp32
            int e = (W - 192 * QTILES) * 64 + lane;   // [0, 4096)
            wT[e] = ldin(w_proj, (e & 63) * CDIM + (e >> 6), f);
        }
    }
    grid_barrier(&bar[0]);

    // ---------------- Phase 2: attention (2 tasks/block, 8-way j-split) --------
    for (int rep = 0; rep < 2; ++rep) {
        int task = b + rep * NBLK;            // [0, 864)
        int h    = task / QTILES;
        int n    = (task % QTILES) * 64 + lane;
        const float2 q = ((const float2*)(Q + h * N_TOK * 2))[n]; // pre-scaled
        const float4* __restrict__ KVp =
            (const float4*)KV + h * N_TOK + wav * JCHUNK;

        float l = 0.f, oa = 0.f, ob = 0.f;
        for (int g = 0; g < JCHUNK; g += 8) {   // 27 groups of 8 keys
            float4 k[8];
#pragma unroll
            for (int u = 0; u < 8; ++u) k[u] = KVp[g + u];  // 8 s_loads in flight
#pragma unroll
            for (int u = 0; u < 8; ++u) {
                // native v_exp_f32 (log2e folded into q); no max-subtract needed
                float e = __builtin_amdgcn_exp2f(fmaf(q.x, k[u].x, q.y * k[u].y));
                l  += e;
                oa  = fmaf(e, k[u].z, oa);
                ob  = fmaf(e, k[u].w, ob);
            }
        }
        float* red = redbuf + wav * 192 + lane * 3;  // stride-3: 2-way alias (free)
        red[0] = l; red[1] = oa; red[2] = ob;
        __syncthreads();
        if (wav == 0) {
            float L = 0.f, A = 0.f, B = 0.f;
#pragma unroll
            for (int w = 0; w < JW; ++w) {
                const float* r = redbuf + w * 192 + lane * 3;
                L += r[0]; A += r[1]; B += r[2];
            }
            float inv = 1.0f / L;
            __hip_bfloat162 o;
            o.x = __float2bfloat16(A * inv);
            o.y = __float2bfloat16(B * inv);
            *((__hip_bfloat162*)(Ob + n * CDIM + 2 * h)) = o;  // 4B-aligned
        }
        __syncthreads();   // protect redbuf before reuse
    }
    grid_barrier(&bar[1]);

    // ---------------- Phase 3: output projection (1 token/wave) ----------------
    if (W0 < N_TOK) {
        int n = W0;
        float acc = ldin(b_proj, lane, f);
#pragma unroll 8
        for (int ci = 0; ci < CDIM; ++ci)
            acc = fmaf(ldin(Ob, n * CDIM + ci, 0),     // uniform row: broadcast
                       wT[ci * CDIM + lane], acc);      // coalesced fp32
        if (f) ((float*)out)[n * CDIM + lane] = acc;
        else   ((__hip_bfloat16*)out)[n * CDIM + lane] = __float2bfloat16(acc);
    }
}

extern "C" void kernel_launch(void* const* d_in, const int* in_sizes, int n_in,
                              void* d_out, int out_size, void* d_ws, size_t ws_size,
                              hipStream_t stream) {
    const void* x      = d_in[0];
    const void* w_qkv  = d_in[1];
    const void* w_proj = d_in[2];
    const void* b_proj = d_in[3];

    // ws layout (~1.57 MB; proven budget >= 1.77 MB):
    unsigned int* bar = (unsigned int*)d_ws;             // 2 counters in first 256 B
    float* Q  = (float*)((char*)d_ws + 256);             // 442368 B
    float* KV = Q  + NHEADS * N_TOK * 2;                 // 884736 B, 16B-aligned
    float* wT = KV + NHEADS * N_TOK * 4;                 // 16384 B
    __hip_bfloat16* Ob = (__hip_bfloat16*)(wT + CDIM * CDIM); // 221184 B

    // zero the barrier counters every launch (ws is re-poisoned to 0xAA)
    hipMemsetAsync(bar, 0, 256, stream);
    fused_kernel<<<NBLK, 512, 0, stream>>>(x, w_qkv, w_proj, b_proj,
                                           bar, Q, KV, wT, Ob, d_out);
}

// Round 7
// 117.926 us; speedup vs baseline: 2.4937x; 2.4937x over previous
//
#include <hip/hip_runtime.h>
#include <hip/hip_bf16.h>

#define N_TOK  1728     // 12*12*12
#define CDIM   64
#define NHEADS 32       // head_dim = 2
#define QTILES 27       // 1728 / 64
#define SCALE  0.70710678118654752f    // 1/sqrt(2)
#define LOG2E  1.44269504088896340736f
#define JW     8                       // waves per attn block (j-split)
#define JCHUNK (N_TOK / JW)            // 216 keys per wave

// ---- dtype-adaptive load: f32=1 -> fp32 buffer, 0 -> bf16 buffer ----
__device__ __forceinline__ float ldin(const void* p, int i, int f32) {
    if (f32) return ((const float*)p)[i];
    union { unsigned int b; float f; } c;
    c.b = ((unsigned int)((const unsigned short*)p)[i]) << 16;
    return c.f;
}

// ---- wave-local dtype sniff: fp32 bits read as bf16 show exp=0xFF / huge ----
__device__ __forceinline__ int sniff_f32(const void* x) {
    union { unsigned int b; float f; } c;
    c.b = ((unsigned int)((const unsigned short*)x)[threadIdx.x & 63]) << 16;
    int bad = (((c.b >> 23) & 0xFF) == 0xFF) || (fabsf(c.f) > 1e10f);
    return (__ballot(bad) != 0ULL) ? 1 : 0;
}

// ========== Kernel 1: fused QKV + attention (no cross-block deps) ==========
// grid 864 = 32 heads x 27 q-tiles, block 512 (8 waves).
// Each block recomputes its head's K/V for ALL tokens into LDS (x is
// L2-resident; ~27x head-tile redundancy costs ~8 us chip-wide VALU),
// computes Q for its 64 queries, then 8-way j-split attention from LDS.
// Only block-local __syncthreads — kernel-boundary coherence handles the rest.
__global__ void __launch_bounds__(512, 4)
attn_fused(const void* __restrict__ x, const void* __restrict__ w_qkv,
           __hip_bfloat16* __restrict__ Ob) {
    __shared__ float4 KVs[N_TOK];          // 27648 B  {k0,k1,v0,v1}
    __shared__ float  wrow[6][CDIM];       //  1536 B  q0,q1,k0,k1,v0,v1 rows
    __shared__ float2 Qs[64];              //   512 B  pre-scaled queries
    __shared__ float  redbuf[JW * 64 * 3]; //  6144 B  cross-wave reduction
    const int f    = sniff_f32(x);
    const int tid  = threadIdx.x;
    const int lane = tid & 63;
    const int wav  = tid >> 6;
    const int h    = blockIdx.x / QTILES;
    const int t0   = (blockIdx.x % QTILES) * 64;

    // stage the 6 weight rows for this head (uniform rows -> broadcast reads)
    for (int e = tid; e < 6 * CDIM; e += 512) {
        int r = e >> 6, c = e & 63;
        int row = (r >> 1) * CDIM + 2 * h + (r & 1);  // q:0-63, k:64-127, v:128-191
        wrow[r][c] = ldin(w_qkv, row * CDIM + c, f);
    }
    __syncthreads();

    // per-thread token KV (+Q when the 64-token chunk == this block's tile;
    // chunks are 64-aligned so the branch is wave-uniform)
    for (int it = 0; it < 4; ++it) {
        int n = it * 512 + tid;
        if (n < N_TOK) {                      // wave-uniform (1728 = 27 waves)
            float k0 = 0.f, k1 = 0.f, v0 = 0.f, v1 = 0.f;
            if ((n & ~63) == t0) {            // wave-uniform: compute Q too
                float q0 = 0.f, q1 = 0.f;
#pragma unroll 8
                for (int c = 0; c < CDIM; ++c) {
                    float xv = ldin(x, c * N_TOK + n, f);   // coalesced lanes
                    q0 = fmaf(xv, wrow[0][c], q0); q1 = fmaf(xv, wrow[1][c], q1);
                    k0 = fmaf(xv, wrow[2][c], k0); k1 = fmaf(xv, wrow[3][c], k1);
                    v0 = fmaf(xv, wrow[4][c], v0); v1 = fmaf(xv, wrow[5][c], v1);
                }
                Qs[n - t0] = make_float2(q0 * (SCALE * LOG2E),
                                         q1 * (SCALE * LOG2E));
            } else {
#pragma unroll 8
                for (int c = 0; c < CDIM; ++c) {
                    float xv = ldin(x, c * N_TOK + n, f);
                    k0 = fmaf(xv, wrow[2][c], k0); k1 = fmaf(xv, wrow[3][c], k1);
                    v0 = fmaf(xv, wrow[4][c], v0); v1 = fmaf(xv, wrow[5][c], v1);
                }
            }
            KVs[n] = make_float4(k0, k1, v0, v1);
        }
    }
    __syncthreads();

    // attention: wave w streams keys [w*216, (w+1)*216) from LDS (broadcast,
    // conflict-free). Native v_exp_f32; no max-subtract (|s·log2e| << 127).
    float2 q = Qs[lane];
    const float4* KVp = &KVs[wav * JCHUNK];
    float l = 0.f, oa = 0.f, ob = 0.f;
    for (int g = 0; g < JCHUNK; g += 8) {   // 27 groups of 8 keys
        float4 k[8];
#pragma unroll
        for (int u = 0; u < 8; ++u) k[u] = KVp[g + u];  // 8 ds_reads in flight
#pragma unroll
        for (int u = 0; u < 8; ++u) {
            float e = __builtin_amdgcn_exp2f(fmaf(q.x, k[u].x, q.y * k[u].y));
            l  += e;
            oa  = fmaf(e, k[u].z, oa);
            ob  = fmaf(e, k[u].w, ob);
        }
    }
    float* red = redbuf + wav * 192 + lane * 3;  // stride-3: 2-way alias (free)
    red[0] = l; red[1] = oa; red[2] = ob;
    __syncthreads();
    if (wav == 0) {
        float L = 0.f, A = 0.f, B = 0.f;
#pragma unroll
        for (int w = 0; w < JW; ++w) {
            const float* r = redbuf + w * 192 + lane * 3;
            L += r[0]; A += r[1]; B += r[2];
        }
        float inv = 1.0f / L;
        __hip_bfloat162 o;
        o.x = __float2bfloat16(A * inv);
        o.y = __float2bfloat16(B * inv);
        int n = t0 + lane;
        *((__hip_bfloat162*)(Ob + n * CDIM + 2 * h)) = o;  // 4B-aligned
    }
}

// ========== Kernel 2: output projection (self-contained) ==========
// grid 432, block 256 (4 waves = 4 tokens). w_proj staged transposed in
// padded LDS [64][65] (write: lane*65+const -> 2-way; read: consecutive).
__global__ void __launch_bounds__(256)
proj_kernel(const void* __restrict__ x,   // dtype sniff only
            const __hip_bfloat16* __restrict__ Ob,
            const void* __restrict__ w_proj, const void* __restrict__ b_proj,
            void* __restrict__ out) {
    __shared__ float Ws[CDIM * 65];        // 16640 B, transposed w_proj
    const int f    = sniff_f32(x);
    const int tid  = threadIdx.x;
    const int lane = tid & 63;
    const int wav  = tid >> 6;
    for (int e = tid; e < CDIM * CDIM; e += 256) {   // e = co*64+ci, coalesced
        Ws[(e & 63) * 65 + (e >> 6)] = ldin(w_proj, e, f);
    }
    __syncthreads();
    int n = blockIdx.x * 4 + wav;          // 432*4 = 1728
    float acc = ldin(b_proj, lane, f);
#pragma unroll 8
    for (int ci = 0; ci < CDIM; ++ci)
        acc = fmaf(ldin(Ob, n * CDIM + ci, 0),       // uniform row: broadcast
                   Ws[ci * 65 + lane], acc);          // conflict-free
    if (f) ((float*)out)[n * CDIM + lane] = acc;
    else   ((__hip_bfloat16*)out)[n * CDIM + lane] = __float2bfloat16(acc);
}

extern "C" void kernel_launch(void* const* d_in, const int* in_sizes, int n_in,
                              void* d_out, int out_size, void* d_ws, size_t ws_size,
                              hipStream_t stream) {
    const void* x      = d_in[0];
    const void* w_qkv  = d_in[1];
    const void* w_proj = d_in[2];
    const void* b_proj = d_in[3];

    __hip_bfloat16* Ob = (__hip_bfloat16*)d_ws;   // [1728][64] bf16, 221184 B

    attn_fused <<<NHEADS * QTILES, 512, 0, stream>>>(x, w_qkv, Ob);
    proj_kernel<<<432, 256, 0, stream>>>(x, Ob, w_proj, b_proj, d_out);
}